// Round 11
// baseline (1602.490 us; speedup 1.0000x reference)
//
#include <hip/hip_runtime.h>

typedef __attribute__((ext_vector_type(4))) float  f4;
typedef __attribute__((ext_vector_type(2))) float  f2;
typedef __attribute__((ext_vector_type(4))) unsigned short us4;
typedef __attribute__((ext_vector_type(8))) short  s8;     // bf16x8 MFMA frag
typedef __attribute__((ext_vector_type(4))) float  f32x4;  // MFMA acc

__device__ __forceinline__ unsigned short f2bf(float f) {
  unsigned u = __float_as_uint(f);
  u += 0x7fffu + ((u >> 16) & 1u);
  return (unsigned short)(u >> 16);
}
__device__ __forceinline__ float elu1(float x) { return x > 0.f ? x + 1.f : __expf(x); }
__device__ __forceinline__ float gelu_erf(float x) { return 0.5f * x * (1.f + erff(x * 0.70710678118654752f)); }

__device__ __forceinline__ void async16(const void* g, void* l) {
  __builtin_amdgcn_global_load_lds((const __attribute__((address_space(1))) void*)g,
                                   (__attribute__((address_space(3))) void*)l, 16, 0, 0);
}

// RAW barrier: no compiler-attached waitcnt drain.
__device__ __forceinline__ void rawbar() {
  asm volatile("s_barrier" ::: "memory");
}

// LDS generic pointer -> 32-bit DS address
__device__ __forceinline__ unsigned l2u(const void* p) {
  return (unsigned)(size_t)(const __attribute__((address_space(3))) char*)p;
}
// asm ds_read_b128 with compile-time immediate offset
template<int OFF>
__device__ __forceinline__ void dsr(s8& d, unsigned base) {
  asm volatile("ds_read_b128 %0, %1 offset:%2" : "=v"(d) : "v"(base), "i"(OFF));
}

// ---------------- embedding: X = tok[idx] + pos, also bf16 copy ----------------
__global__ __launch_bounds__(256) void embed_kernel(
    const int* __restrict__ idx, const float* __restrict__ tok,
    const float* __restrict__ pos, float* __restrict__ X, unsigned short* __restrict__ XB)
{
  int g = blockIdx.x * 256 + threadIdx.x;
  int t = g >> 8;
  int c4 = (g & 255) * 4;
  int l = t & 2047;
  int tk = idx[t];
  f4 v = *(const f4*)(tok + (size_t)tk * 1024 + c4);
  f4 p = *(const f4*)(pos + (size_t)l * 1024 + c4);
  v += p;
  *(f4*)(X + (size_t)t * 1024 + c4) = v;
  us4 o = { f2bf(v[0]), f2bf(v[1]), f2bf(v[2]), f2bf(v[3]) };
  *(us4*)(XB + (size_t)t * 1024 + c4) = o;
}

// ---------------- f32 [K,N] -> bf16 [N,K] transpose-convert ----------------
__global__ __launch_bounds__(256) void transpose_cvt(
    const float* __restrict__ src, unsigned short* __restrict__ dst, int N, int K)
{
  __shared__ unsigned short t[64][72];
  int k0 = blockIdx.x * 64, n0 = blockIdx.y * 64;
  int tid = threadIdx.x;
#pragma unroll
  for (int i = 0; i < 4; ++i) {
    int f = tid + i * 256;
    int r = f >> 4, c4 = (f & 15) * 4;
    f4 v = *(const f4*)(src + (size_t)(k0 + r) * N + n0 + c4);
    us4 o = { f2bf(v[0]), f2bf(v[1]), f2bf(v[2]), f2bf(v[3]) };
    *(us4*)&t[r][c4] = o;
  }
  __syncthreads();
#pragma unroll
  for (int i = 0; i < 4; ++i) {
    int f = tid + i * 256;
    int nr = f >> 4, kc4 = (f & 15) * 4;
    us4 o = { t[kc4 + 0][nr], t[kc4 + 1][nr], t[kc4 + 2][nr], t[kc4 + 3][nr] };
    *(us4*)(dst + (size_t)(n0 + nr) * K + k0 + kc4) = o;
  }
}

// ---------------- 128x128 bf16 MFMA GEMM (QKV, fallback) ----------------
template<int EPI, int BF32>
__global__ __launch_bounds__(256) void gemm_bt(
    const unsigned short* __restrict__ A, const unsigned short* __restrict__ Bt,
    const float* __restrict__ Bf, const float* __restrict__ bias,
    void* __restrict__ Cv, int M, int N, int K, int mtiles)
{
  __shared__ unsigned short As[128 * 32];
  __shared__ unsigned short Bs[128 * 32];
  int bid = blockIdx.x;
  int mt = bid % mtiles, nt = bid / mtiles;
  int m0 = mt * 128, n0 = nt * 128;
  int tid = threadIdx.x, lane = tid & 63, w = tid >> 6;
  int wm = (w & 1) * 64, wn = (w >> 1) * 64;

  int c0 = w * 128 + lane, c1 = c0 + 64;
  size_t aO0 = (size_t)(m0 + (c0 >> 2)) * K + (size_t)((c0 & 3) * 8);
  size_t aO1 = (size_t)(m0 + (c1 >> 2)) * K + (size_t)((c1 & 3) * 8);
  size_t bO0 = (size_t)(n0 + (c0 >> 2)) * K + (size_t)((c0 & 3) * 8);
  size_t bO1 = (size_t)(n0 + (c1 >> 2)) * K + (size_t)((c1 & 3) * 8);
  unsigned short* lA0 = As + (w * 128) * 8;
  unsigned short* lA1 = As + (w * 128 + 64) * 8;
  unsigned short* lB0 = Bs + (w * 128) * 8;
  unsigned short* lB1 = Bs + (w * 128 + 64) * 8;

  f32x4 acc[4][4];
  f32x4 zz = {0.f, 0.f, 0.f, 0.f};
#pragma unroll
  for (int i = 0; i < 4; ++i)
#pragma unroll
    for (int j = 0; j < 4; ++j) acc[i][j] = zz;

  int rr = lane & 15, kh = (lane >> 4) * 8;
  const unsigned short* Ar = As + (wm + rr) * 32 + kh;
  const unsigned short* Br = Bs + (wn + rr) * 32 + kh;

  for (int k0 = 0; k0 < K; k0 += 32) {
    async16(A + aO0 + k0, lA0);
    async16(A + aO1 + k0, lA1);
    if constexpr (!BF32) {
      async16(Bt + bO0 + k0, lB0);
      async16(Bt + bO1 + k0, lB1);
    } else {
#pragma unroll
      for (int i = 0; i < 4; ++i) {
        int f = tid + i * 256;
        int kr = f >> 5, c4 = (f & 31) * 4;
        f4 v = *(const f4*)(Bf + (size_t)(k0 + kr) * N + n0 + c4);
#pragma unroll
        for (int e = 0; e < 4; ++e) Bs[(c4 + e) * 32 + kr] = f2bf(v[e]);
      }
    }
    __syncthreads();
    s8 af[4], bfr[4];
#pragma unroll
    for (int mi = 0; mi < 4; ++mi) af[mi] = *(const s8*)(Ar + mi * 512);
#pragma unroll
    for (int ni = 0; ni < 4; ++ni) bfr[ni] = *(const s8*)(Br + ni * 512);
#pragma unroll
    for (int mi = 0; mi < 4; ++mi)
#pragma unroll
      for (int ni = 0; ni < 4; ++ni)
        acc[mi][ni] = __builtin_amdgcn_mfma_f32_16x16x32_bf16(af[mi], bfr[ni], acc[mi][ni], 0, 0, 0);
    __syncthreads();
  }

  int cr = (lane >> 4) * 4;
#pragma unroll
  for (int mi = 0; mi < 4; ++mi) {
#pragma unroll
    for (int ni = 0; ni < 4; ++ni) {
      int gc = n0 + wn + ni * 16 + rr;
      float bv = (EPI > 0) ? bias[gc] : 0.f;
#pragma unroll
      for (int r = 0; r < 4; ++r) {
        int gr = m0 + wm + mi * 16 + cr + r;
        float v = acc[mi][ni][r] + bv;
        if constexpr (EPI == 1) {
          ((unsigned short*)Cv)[(size_t)gr * N + gc] = f2bf(gelu_erf(v));
        } else {
          ((float*)Cv)[(size_t)gr * N + gc] = v;
        }
      }
    }
  }
}

// ====== 256x256 bf16 GEMM v3: single-barrier tile, chunk-pipelined reads ====
// 512 thr = 8 waves (2M x 4N); BK=64; LDS 128KB; fragment-contiguous layout
// (0 bank conflicts). Per K-tile: 4 chunks of 16 MFMA, chunk c = (kstep, Nhalf)
// in order (0,0)(0,1)(1,0)(1,1). Reads issue ONE CHUNK AHEAD (10/2/10/2), so
// each lgkm wall (2/10/2/0, FIFO per-wave) waits only for reads that had a
// full MFMA chunk of cover, and the LDS queue drains UNDER the MFMA stream
// (r10's all-up-front issue flooded the queue: first wall ate ~1000cyc).
// The last chunk's MFMAs run AFTER the barrier, covering the next tile's
// first read burst. Ledger: RAW global->LDS: vmcnt(8) before the barrier
// certifies tile t+1's 8 stages (t+2's 8 outstanding); WAR LDS: stage of buf
// bt issues after own lgkmcnt(0) (all own reads served); cross-wave reads
// entered the DS queue >=1 chunk earlier and are served before the staging
// writeback lands (>=200-900cyc vmem latency; same race shape validated
// r5/r7/r10). Registers: af0/af1[8]+bf0/bf1[4] static double-buffer; M(c3)
// reads REGISTERS (landed at wall c3) so post-barrier execution is safe.
template<int EPI>  // 1 = bias+GELU->bf16, 2 = bias->f32
__global__ __launch_bounds__(512) void gemm3(
    const unsigned short* __restrict__ A, const unsigned short* __restrict__ Bt,
    const float* __restrict__ bias, void* __restrict__ Cv,
    int M, int N, int K, int mtiles)
{
  __shared__ __align__(16) char A0r[32768];
  __shared__ __align__(16) char B0r[32768];
  __shared__ __align__(16) char A1r[32768];
  __shared__ __align__(16) char B1r[32768];

  const int tid = threadIdx.x, lane = tid & 63, w = tid >> 6;
  const int wm = w >> 2, wn = w & 3;
  const int NT = K >> 6;

  // bijective XCD swizzle (m204)
  int nwg = gridDim.x, orig = blockIdx.x;
  int q = nwg >> 3, r = nwg & 7;
  int xcd = orig & 7, lin = orig >> 3;
  int swz = (xcd < r ? xcd * (q + 1) : r * (q + 1) + (xcd - r) * q) + lin;
  int mt = swz % mtiles, nt = swz / mtiles;
  int m0 = mt * 256, n0 = nt * 256;

  // staging (r5/r10-proven): per-lane global source, wave-uniform LDS dest
  const size_t klane8 = (size_t)((lane >> 4) << 3);
  const size_t arow0 = (size_t)(m0 + w * 32 + (lane & 15)) * K;
  const size_t arow1 = arow0 + (size_t)16 * K;
  const size_t brow0 = (size_t)(n0 + w * 32 + (lane & 15)) * K;
  const size_t brow1 = brow0 + (size_t)16 * K;

  auto stgA = [&](char* reg, int kt, int kb) {
    int ktc = kt < NT ? kt : NT - 1;
    size_t kk = (size_t)ktc * 64 + (size_t)(kb * 32) + klane8;
    char* d = reg + w * 4096 + kb * 1024;
    async16(A + arow0 + kk, d);
    async16(A + arow1 + kk, d + 2048);
  };
  auto stgB = [&](char* reg, int kt, int kb) {
    int ktc = kt < NT ? kt : NT - 1;
    size_t kk = (size_t)ktc * 64 + (size_t)(kb * 32) + klane8;
    char* d = reg + w * 4096 + kb * 1024;
    async16(Bt + brow0 + kk, d);
    async16(Bt + brow1 + kk, d + 2048);
  };

  // fragment read bases (32-bit DS addresses)
  const unsigned AB0 = l2u(A0r + wm * 16384 + lane * 16);
  const unsigned BB0 = l2u(B0r + wn * 8192 + lane * 16);
  const unsigned AB1 = l2u(A1r + wm * 16384 + lane * 16);
  const unsigned BB1 = l2u(B1r + wn * 8192 + lane * 16);

  f32x4 acc[8][4];
  f32x4 zz = {0.f, 0.f, 0.f, 0.f};
#pragma unroll
  for (int i = 0; i < 8; ++i)
#pragma unroll
    for (int j = 0; j < 4; ++j) acc[i][j] = zz;
  s8 af0[8], af1[8], bf0[4], bf1[4];

  // read-issue helpers (fragment-contiguous: A block (f,kb) at (f*2+kb)KB,
  // B block (n,kb) at (n*2+kb)KB within the wave's section)
  auto readC0 = [&](unsigned AB, unsigned BB) {  // 10 reads: A[*][kb0], B[0,1][kb0]
    dsr<(0 * 2 + 0) * 1024>(af0[0], AB);
    dsr<(1 * 2 + 0) * 1024>(af0[1], AB);
    dsr<(2 * 2 + 0) * 1024>(af0[2], AB);
    dsr<(3 * 2 + 0) * 1024>(af0[3], AB);
    dsr<(4 * 2 + 0) * 1024>(af0[4], AB);
    dsr<(5 * 2 + 0) * 1024>(af0[5], AB);
    dsr<(6 * 2 + 0) * 1024>(af0[6], AB);
    dsr<(7 * 2 + 0) * 1024>(af0[7], AB);
    dsr<(0 * 2 + 0) * 1024>(bf0[0], BB);
    dsr<(1 * 2 + 0) * 1024>(bf0[1], BB);
  };
  auto readC1 = [&](unsigned BB) {               // 2 reads: B[2,3][kb0]
    dsr<(2 * 2 + 0) * 1024>(bf0[2], BB);
    dsr<(3 * 2 + 0) * 1024>(bf0[3], BB);
  };
  auto readC2 = [&](unsigned AB, unsigned BB) {  // 10 reads: A[*][kb1], B[0,1][kb1]
    dsr<(0 * 2 + 1) * 1024>(af1[0], AB);
    dsr<(1 * 2 + 1) * 1024>(af1[1], AB);
    dsr<(2 * 2 + 1) * 1024>(af1[2], AB);
    dsr<(3 * 2 + 1) * 1024>(af1[3], AB);
    dsr<(4 * 2 + 1) * 1024>(af1[4], AB);
    dsr<(5 * 2 + 1) * 1024>(af1[5], AB);
    dsr<(6 * 2 + 1) * 1024>(af1[6], AB);
    dsr<(7 * 2 + 1) * 1024>(af1[7], AB);
    dsr<(0 * 2 + 1) * 1024>(bf1[0], BB);
    dsr<(1 * 2 + 1) * 1024>(bf1[1], BB);
  };
  auto readC3 = [&](unsigned BB) {               // 2 reads: B[2,3][kb1]
    dsr<(2 * 2 + 1) * 1024>(bf1[2], BB);
    dsr<(3 * 2 + 1) * 1024>(bf1[3], BB);
  };

  // prologue: stage tile0->buf0, tile1->buf1; certify tile0; pre-issue c0,c1
  stgA(A0r, 0, 0); stgA(A0r, 0, 1); stgB(B0r, 0, 0); stgB(B0r, 0, 1);
  stgA(A1r, 1, 0); stgA(A1r, 1, 1); stgB(B1r, 1, 0); stgB(B1r, 1, 1);
  asm volatile("s_waitcnt vmcnt(8)" ::: "memory");
  rawbar();
  readC0(AB0, BB0);
  readC1(BB0);

  for (int t = 0; t < NT; ++t) {
    const int odd = t & 1;
    const unsigned AB = odd ? AB1 : AB0;
    const unsigned BB = odd ? BB1 : BB0;
    const unsigned ABn = odd ? AB0 : AB1;
    const unsigned BBn = odd ? BB0 : BB1;
    char* Ad = odd ? A1r : A0r;
    char* Bd = odd ? B1r : B0r;

    // wall c0 (af0 + bf0[0,1] ready; bf0[2,3] outstanding) -> M(c0)
    asm volatile("s_waitcnt lgkmcnt(2)" ::: "memory");
    __builtin_amdgcn_sched_barrier(0);
    __builtin_amdgcn_s_setprio(1);
#pragma unroll
    for (int f = 0; f < 8; ++f) {
      acc[f][0] = __builtin_amdgcn_mfma_f32_16x16x32_bf16(af0[f], bf0[0], acc[f][0], 0, 0, 0);
      acc[f][1] = __builtin_amdgcn_mfma_f32_16x16x32_bf16(af0[f], bf0[1], acc[f][1], 0, 0, 0);
    }
    __builtin_amdgcn_s_setprio(0);
    __builtin_amdgcn_sched_barrier(0);

    readC2(AB, BB);  // 10 reads issue under M(c0)'s tail / before wall c1

    // wall c1 (bf0[2,3] ready; c2's 10 outstanding) -> M(c1)
    asm volatile("s_waitcnt lgkmcnt(10)" ::: "memory");
    __builtin_amdgcn_sched_barrier(0);
    __builtin_amdgcn_s_setprio(1);
#pragma unroll
    for (int f = 0; f < 8; ++f) {
      acc[f][2] = __builtin_amdgcn_mfma_f32_16x16x32_bf16(af0[f], bf0[2], acc[f][2], 0, 0, 0);
      acc[f][3] = __builtin_amdgcn_mfma_f32_16x16x32_bf16(af0[f], bf0[3], acc[f][3], 0, 0, 0);
    }
    __builtin_amdgcn_s_setprio(0);
    __builtin_amdgcn_sched_barrier(0);

    readC3(BB);  // 2 reads

    // wall c2 (af1 + bf1[0,1] ready; bf1[2,3] outstanding) -> M(c2)
    asm volatile("s_waitcnt lgkmcnt(2)" ::: "memory");
    __builtin_amdgcn_sched_barrier(0);
    __builtin_amdgcn_s_setprio(1);
#pragma unroll
    for (int f = 0; f < 8; ++f) {
      acc[f][0] = __builtin_amdgcn_mfma_f32_16x16x32_bf16(af1[f], bf1[0], acc[f][0], 0, 0, 0);
      acc[f][1] = __builtin_amdgcn_mfma_f32_16x16x32_bf16(af1[f], bf1[1], acc[f][1], 0, 0, 0);
    }
    __builtin_amdgcn_s_setprio(0);
    __builtin_amdgcn_sched_barrier(0);

    // wall c3: all own reads of this buffer served -> safe to restage it
    asm volatile("s_waitcnt lgkmcnt(0)" ::: "memory");
    __builtin_amdgcn_sched_barrier(0);
    stgA(Ad, t + 2, 0); stgA(Ad, t + 2, 1);
    stgB(Bd, t + 2, 0); stgB(Bd, t + 2, 1);

    // certify tile t+1's staging; open the other buffer
    asm volatile("s_waitcnt vmcnt(8)" ::: "memory");
    rawbar();

    // next tile's first reads issue NOW; M(c3) (register-only) covers them
    readC0(ABn, BBn);
    readC1(BBn);

    __builtin_amdgcn_s_setprio(1);
#pragma unroll
    for (int f = 0; f < 8; ++f) {
      acc[f][2] = __builtin_amdgcn_mfma_f32_16x16x32_bf16(af1[f], bf1[2], acc[f][2], 0, 0, 0);
      acc[f][3] = __builtin_amdgcn_mfma_f32_16x16x32_bf16(af1[f], bf1[3], acc[f][3], 0, 0, 0);
    }
    __builtin_amdgcn_s_setprio(0);
    __builtin_amdgcn_sched_barrier(0);
  }

  // drain everything (incl. dead next-tile reads) before epilogue
  asm volatile("s_waitcnt vmcnt(0) lgkmcnt(0)" ::: "memory");
  __builtin_amdgcn_sched_barrier(0);

  // epilogue: C/D map col=lane&15, row=(lane>>4)*4+reg
  int rr = lane & 15, cr = (lane >> 4) * 4;
#pragma unroll
  for (int f = 0; f < 8; ++f) {
#pragma unroll
    for (int ni = 0; ni < 4; ++ni) {
      int gc = n0 + wn * 64 + ni * 16 + rr;
      float bv = bias[gc];
#pragma unroll
      for (int rg = 0; rg < 4; ++rg) {
        int gr = m0 + wm * 128 + f * 16 + cr + rg;
        float v = acc[f][ni][rg] + bv;
        if constexpr (EPI == 1) {
          ((unsigned short*)Cv)[(size_t)gr * N + gc] = f2bf(gelu_erf(v));
        } else {
          ((float*)Cv)[(size_t)gr * N + gc] = v;
        }
      }
    }
  }
}

// ---------------- per-chunk K^T V and K sums ----------------
__global__ __launch_bounds__(256) void chunk_sums(
    const float* __restrict__ QKV, float* __restrict__ KVc, float* __restrict__ Ksum)
{
  __shared__ float Ks[64][68], Vs[64][68];
  int blk = blockIdx.x, t0 = blk * 64, tid = threadIdx.x;
#pragma unroll
  for (int i = 0; i < 4; ++i) {
    int f = tid + i * 256;
    int r = f >> 4, c4 = (f & 15) * 4;
    const float* s = QKV + (size_t)(t0 + r) * 256;
    f4 k = *(const f4*)(s + 64 + c4);
    f4 v = *(const f4*)(s + 128 + c4);
#pragma unroll
    for (int e = 0; e < 4; ++e) { Ks[r][c4 + e] = elu1(k[e]); Vs[r][c4 + e] = v[e]; }
  }
  __syncthreads();
  int i0 = tid >> 2, jb = (tid & 3) * 16;
  f4 a0 = {0,0,0,0}, a1 = {0,0,0,0}, a2 = {0,0,0,0}, a3 = {0,0,0,0};
  for (int t = 0; t < 64; ++t) {
    float kk = Ks[t][i0];
    a0 += kk * (*(const f4*)&Vs[t][jb]);
    a1 += kk * (*(const f4*)&Vs[t][jb + 4]);
    a2 += kk * (*(const f4*)&Vs[t][jb + 8]);
    a3 += kk * (*(const f4*)&Vs[t][jb + 12]);
  }
  float* d = KVc + (size_t)blk * 4096 + i0 * 64 + jb;
  *(f4*)(d) = a0; *(f4*)(d + 4) = a1; *(f4*)(d + 8) = a2; *(f4*)(d + 12) = a3;
  if (tid < 64) {
    float s = 0.f;
    for (int t = 0; t < 64; ++t) s += Ks[t][tid];
    Ksum[(size_t)blk * 64 + tid] = s;
  }
}

// ---------------- exclusive prefix of chunk states ----------------
__global__ __launch_bounds__(256) void prefix_state(
    const float* __restrict__ KVc, const float* __restrict__ Ksum,
    float* __restrict__ KVp, float* __restrict__ Ksump)
{
  int b = blockIdx.x >> 3, seg = blockIdx.x & 7;
  int e = seg * 512 + threadIdx.x * 2;
  f2 run = {0.f, 0.f};
#pragma unroll
  for (int c = 0; c < 32; ++c) {
    size_t base = ((size_t)b * 32 + c) * 4096 + e;
    *(f2*)(KVp + base) = run;
    run += *(const f2*)(KVc + base);
  }
  if (seg == 0 && threadIdx.x < 64) {
    float rs = 0.f; int i = threadIdx.x;
#pragma unroll
    for (int c = 0; c < 32; ++c) {
      size_t base = ((size_t)b * 32 + c) * 64 + i;
      Ksump[base] = rs;
      rs += Ksum[base];
    }
  }
}

// ---------------- per-chunk normalized attention coefficients ----------------
__global__ __launch_bounds__(256) void attn_ns(
    const float* __restrict__ QKV, const float* __restrict__ KVp,
    const float* __restrict__ Ksump, float* __restrict__ NsG)
{
  __shared__ float Qs[64][68], Ks[64][68], Vs[64][68], Ss[64][68], Ps[64][68];
  __shared__ float ksps[64];
  int blk = blockIdx.x, t0 = blk * 64, tid = threadIdx.x;
#pragma unroll
  for (int i = 0; i < 4; ++i) {
    int f = tid + i * 256;
    int r = f >> 4, c4 = (f & 15) * 4;
    const float* s = QKV + (size_t)(t0 + r) * 256;
    f4 q = *(const f4*)(s + c4);
    f4 k = *(const f4*)(s + 64 + c4);
    f4 v = *(const f4*)(s + 128 + c4);
    f4 p = *(const f4*)(KVp + (size_t)blk * 4096 + r * 64 + c4);
#pragma unroll
    for (int e = 0; e < 4; ++e) {
      Qs[r][c4 + e] = elu1(q[e]); Ks[r][c4 + e] = elu1(k[e]);
      Vs[r][c4 + e] = v[e];       Ps[r][c4 + e] = p[e];
    }
  }
  if (tid < 64) ksps[tid] = Ksump[(size_t)blk * 64 + tid];
  __syncthreads();
  int tq = tid >> 2, jb = (tid & 3) * 16;
#pragma unroll
  for (int jj = 0; jj < 16; ++jj) {
    int tk = jb + jj;
    float s = 0.f;
    if (tk <= tq) {
#pragma unroll
      for (int k4 = 0; k4 < 16; ++k4) {
        f4 q = *(const f4*)&Qs[tq][k4 * 4];
        f4 k = *(const f4*)&Ks[tk][k4 * 4];
        s += q[0] * k[0] + q[1] * k[1] + q[2] * k[2] + q[3] * k[3];
      }
    }
    Ss[tq][tk] = s;
  }
  __syncthreads();
  f4 a0 = {0,0,0,0}, a1 = {0,0,0,0}, a2 = {0,0,0,0}, a3 = {0,0,0,0};
  for (int t = 0; t < 64; ++t) {
    float s = Ss[tq][t];
    a0 += s * (*(const f4*)&Vs[t][jb]);
    a1 += s * (*(const f4*)&Vs[t][jb + 4]);
    a2 += s * (*(const f4*)&Vs[t][jb + 8]);
    a3 += s * (*(const f4*)&Vs[t][jb + 12]);
  }
  for (int k = 0; k < 64; ++k) {
    float q = Qs[tq][k];
    a0 += q * (*(const f4*)&Ps[k][jb]);
    a1 += q * (*(const f4*)&Ps[k][jb + 4]);
    a2 += q * (*(const f4*)&Ps[k][jb + 8]);
    a3 += q * (*(const f4*)&Ps[k][jb + 12]);
  }
  float den = 0.f;
  for (int t = 0; t < 64; ++t) den += Ss[tq][t];
  for (int k = 0; k < 64; ++k) den += Qs[tq][k] * ksps[k];
  float inv = 1.f / (den + 1e-6f);
  float* d = NsG + (size_t)(t0 + tq) * 64 + jb;
  *(f4*)(d)      = a0 * inv;
  *(f4*)(d + 4)  = a1 * inv;
  *(f4*)(d + 8)  = a2 * inv;
  *(f4*)(d + 12) = a3 * inv;
}

// ---------------- attn @ Wo + residual into X ----------------
__global__ __launch_bounds__(256) void attn_apply(
    const float* __restrict__ NsG, const float* __restrict__ Wo, float* __restrict__ X)
{
  __shared__ float Ns[64][68];
  __shared__ float Wt[64][260];
  int chunk = blockIdx.x >> 2, dg = blockIdx.x & 3;
  int t0 = chunk * 64, d0 = dg * 256, tid = threadIdx.x;
#pragma unroll
  for (int i = 0; i < 4; ++i) {
    int f = tid + i * 256;
    int r = f >> 4, c4 = (f & 15) * 4;
    *(f4*)&Ns[r][c4] = *(const f4*)(NsG + (size_t)(t0 + r) * 64 + c4);
  }
#pragma unroll
  for (int i = 0; i < 16; ++i) {
    int f = tid + i * 256;
    int r = f >> 6, c4 = (f & 63) * 4;
    *(f4*)&Wt[r][c4] = *(const f4*)(Wo + (size_t)r * 1024 + d0 + c4);
  }
  __syncthreads();
  int w = tid >> 6, lane = tid & 63;
  for (int ts = 0; ts < 16; ++ts) {
    int t = w * 16 + ts;
    float a0 = 0.f, a1 = 0.f, a2 = 0.f, a3 = 0.f;
#pragma unroll
    for (int j = 0; j < 64; ++j) {
      float nv = Ns[t][j];
      a0 += nv * Wt[j][lane];
      a1 += nv * Wt[j][64 + lane];
      a2 += nv * Wt[j][128 + lane];
      a3 += nv * Wt[j][192 + lane];
    }
    size_t o = (size_t)(t0 + t) * 1024 + d0 + lane;
    X[o]       += a0;
    X[o + 64]  += a1;
    X[o + 128] += a2;
    X[o + 192] += a3;
  }
}

// ---------------- layernorm over D=1024, writes f32 + bf16 ----------------
__global__ __launch_bounds__(256) void layernorm_kernel(
    float* __restrict__ X, unsigned short* __restrict__ XB,
    const float* __restrict__ g, const float* __restrict__ b)
{
  int t = blockIdx.x * 4 + (threadIdx.x >> 6);
  int lane = threadIdx.x & 63;
  float* row = X + (size_t)t * 1024;
  f4 v[4];
  float s = 0.f, s2 = 0.f;
#pragma unroll
  for (int i = 0; i < 4; ++i) {
    v[i] = *(const f4*)(row + (i * 64 + lane) * 4);
#pragma unroll
    for (int e = 0; e < 4; ++e) { s += v[i][e]; s2 += v[i][e] * v[i][e]; }
  }
#pragma unroll
  for (int off = 32; off > 0; off >>= 1) {
    s  += __shfl_xor(s, off, 64);
    s2 += __shfl_xor(s2, off, 64);
  }
  float mean = s * (1.f / 1024.f);
  float var = s2 * (1.f / 1024.f) - mean * mean;
  float rstd = rsqrtf(var + 1e-5f);
#pragma unroll
  for (int i = 0; i < 4; ++i) {
    int d = (i * 64 + lane) * 4;
    f4 gv = *(const f4*)(g + d);
    f4 bv = *(const f4*)(b + d);
    f4 y;
#pragma unroll
    for (int e = 0; e < 4; ++e) y[e] = (v[i][e] - mean) * rstd * gv[e] + bv[e];
    *(f4*)(row + d) = y;
    us4 o = { f2bf(y[0]), f2bf(y[1]), f2bf(y[2]), f2bf(y[3]) };
    *(us4*)(XB + (size_t)t * 1024 + d) = o;
  }
}

extern "C" void kernel_launch(void* const* d_in, const int* in_sizes, int n_in,
                              void* d_out, int out_size, void* d_ws, size_t ws_size,
                              hipStream_t stream) {
  (void)in_sizes; (void)n_in; (void)out_size;
  const int*   idx = (const int*)d_in[0];
  const float* tok = (const float*)d_in[1];
  const float* pos = (const float*)d_in[2];
  const float* Wq  = (const float*)d_in[3];
  const float* Wk  = (const float*)d_in[4];
  const float* Wv  = (const float*)d_in[5];
  const float* Wo  = (const float*)d_in[6];
  const float* ng  = (const float*)d_in[7];
  const float* nb  = (const float*)d_in[8];
  const float* ong = (const float*)d_in[9];
  const float* onb = (const float*)d_in[10];
  const float* W1  = (const float*)d_in[11];
  const float* b1  = (const float*)d_in[12];
  const float* W2  = (const float*)d_in[13];
  const float* b2  = (const float*)d_in[14];
  float* out = (float*)d_out;
  char* ws = (char*)d_ws;

  float* X            = (float*)(ws + 0);
  unsigned short* XB  = (unsigned short*)(ws + 16777216);
  unsigned short* QT0 = (unsigned short*)(ws + 25165824);
  unsigned short* QT1 = (unsigned short*)(ws + 25690112);
  float* QKVB         = (float*)(ws + 26214400);
  float* KVC          = (float*)(ws + 30408704);
  float* KSUM         = (float*)(ws + 31457280);
  float* KVP          = (float*)(ws + 31490048);
  float* KSP          = (float*)(ws + 32538624);
  unsigned short* W1T = (unsigned short*)(ws + 32571392);
  unsigned short* H   = (unsigned short*)(ws + 40960000);
  unsigned short* W2T = (unsigned short*)(ws + 74514432);
  float* NSG = KVC;  // reuse: KVC dead after prefix_state
  bool bigws = ws_size >= 336658432ull;

  hipMemsetAsync(QT0, 0, 524288, stream);
  hipMemsetAsync(QT1, 0, 524288, stream);
  transpose_cvt<<<dim3(16, 1), 256, 0, stream>>>(Wq,          QT0,              64, 1024);
  transpose_cvt<<<dim3(16, 1), 256, 0, stream>>>(Wk,          QT0 + 64 * 1024,  64, 1024);
  transpose_cvt<<<dim3(16, 1), 256, 0, stream>>>(Wv,          QT0 + 128 * 1024, 64, 1024);
  transpose_cvt<<<dim3(16, 1), 256, 0, stream>>>(Wq + 65536,  QT1,              64, 1024);
  transpose_cvt<<<dim3(16, 1), 256, 0, stream>>>(Wk + 65536,  QT1 + 64 * 1024,  64, 1024);
  transpose_cvt<<<dim3(16, 1), 256, 0, stream>>>(Wv + 65536,  QT1 + 128 * 1024, 64, 1024);
  transpose_cvt<<<dim3(16, 64), 256, 0, stream>>>(W1, W1T, 4096, 1024);
  if (bigws)
    transpose_cvt<<<dim3(64, 500), 256, 0, stream>>>(W2, W2T, 32000, 4096);

  embed_kernel<<<4096, 256, 0, stream>>>(idx, tok, pos, X, XB);

  for (int layer = 0; layer < 2; ++layer) {
    const unsigned short* QT = layer ? QT1 : QT0;
    gemm_bt<0, 0><<<64, 256, 0, stream>>>(XB, QT, nullptr, nullptr, QKVB, 4096, 256, 1024, 32);
    chunk_sums<<<64, 256, 0, stream>>>(QKVB, KVC, KSUM);
    prefix_state<<<16, 256, 0, stream>>>(KVC, KSUM, KVP, KSP);
    attn_ns<<<64, 256, 0, stream>>>(QKVB, KVP, KSP, NSG);
    attn_apply<<<256, 256, 0, stream>>>(NSG, Wo + (size_t)layer * 65536, X);
    layernorm_kernel<<<1024, 256, 0, stream>>>(X, XB, ng + layer * 1024, nb + layer * 1024);
  }
  layernorm_kernel<<<1024, 256, 0, stream>>>(X, XB, ong, onb);

  gemm3<1><<<256, 512, 0, stream>>>(XB, W1T, b1, H, 4096, 4096, 1024, 16);
  if (bigws)
    gemm3<2><<<2000, 512, 0, stream>>>(H, W2T, b2, out, 4096, 32000, 4096, 16);
  else
    gemm_bt<2, 1><<<8000, 256, 0, stream>>>(H, nullptr, W2, b2, out, 4096, 32000, 4096, 32);
}